// Round 5
// baseline (1035.351 us; speedup 1.0000x reference)
//
#include <hip/hip_runtime.h>
#include <math.h>

// ---------------- problem constants ----------------
#define NI    100000
#define KSEL  1000
#define NCOL2 640          // packed cols: 512 interleaved Wa/Wb pairs | 4 Wcls | 15 Wr | 109 pad
#define HBINS 2048         // radix histogram bins per selection column

// ---------------- d_out layout (floats) ----------------
#define OUT_FS   0
#define OUT_YP   400000
#define OUT_YH   400004
#define OUT_REF  400005
#define OUT_LOSS 900005

// ---------------- workspace layout (float offsets) ----------------
#define OFF_DET    0                 // det_logit N*4
#define OFF_CLS    400000            // cls_score N*4
#define OFF_REF0   800000            // softmax(h@Wr0+br0) N*5
#define OFF_REF1   1300000           // softmax(h@Wr1+br1) N*5
#define OFF_MEAN   1800000           // mean_score N
#define OFF_WPT    1900000           // bf16 packed W^T, FRAGMENT-ORDERED (see prep) = 640KB
#define OFF_BPACK  2063840           // packed bias [640]
#define OFF_SCAL   2064480           // 128 scalar slots
#define OFF_SELIDX 2064608           // 15*1000 ints
#define OFF_HIST   2079608           // (unused now, kept for layout stability)

// scalar slots (index into u32/f32/i32 view of ws+OFF_SCAL)
#define SC_SUMEXP 0     // f[4] det softmax denominator
#define SC_YPROB  4     // f[4]
#define SC_FSMIN  8     // u[4] encoded min of final_score per class
#define SC_FSMAX  12    // u[4]
#define SC_THR    16    // f[4] (unused now, kept)
#define SC_INCL   20    // i[5] (unused now, kept)
#define SC_NUM    25    // f[3] CE numerators
#define SC_CNT    28    // i[15] selected counts
#define SC_PREFIX 43    // u[15] (unused now, kept)
#define SC_RESTK  58    // u[15] (unused now, kept)
#define SC_TICKET 73    // u[1] ce last-block ticket

typedef short short8 __attribute__((ext_vector_type(8)));
typedef float f32x4 __attribute__((ext_vector_type(4)));
typedef unsigned int uint32x4 __attribute__((ext_vector_type(4)));

__device__ __forceinline__ unsigned fenc(float x) {
    unsigned u = __float_as_uint(x);
    return (u & 0x80000000u) ? ~u : (u | 0x80000000u);
}
__device__ __forceinline__ unsigned short f2bf(float f) {
    unsigned u = __float_as_uint(f);
    return (unsigned short)((u + 0x7FFFu + ((u >> 16) & 1u)) >> 16);
}

// ================= kernel 1: pack weights bf16 in FRAGMENT ORDER, biases, init scalars =================
// B layout: seg(cb,s,colblk,nt) = (cb*16+s)*8 + colblk*2 + nt, 640 segs x 1KB.
// Within a seg: lane (lq*16+lrow) holds 8 elems = col(colblk*32+nt*16+lrow), k(s*32+lq*8 ..+8).
// -> each k-loop B load is base + lane*16: ONE coalesced 1KB segment (was a 16..64-line gather).
__global__ __launch_bounds__(256) void prep_kernel(
    const float* __restrict__ Wa, const float* __restrict__ Wb,
    const float* __restrict__ Wcls, const float* __restrict__ Wr,
    const float* __restrict__ ba, const float* __restrict__ bb,
    const float* __restrict__ bcls, const float* __restrict__ br,
    float* __restrict__ ws)
{
    const int tid0 = blockIdx.x * 256 + threadIdx.x;   // grid 1280*256 = 327680 threads
    unsigned short* wpT = (unsigned short*)(ws + OFF_WPT);
    if (tid0 < NCOL2 * 512) {
        const int c = tid0 >> 9, k = tid0 & 511;
        float v = 0.f;
        if (c < 512)      { const int j = c >> 1; v = (c & 1) ? Wb[k*256 + j] : Wa[k*256 + j]; }
        else if (c < 516)   v = Wcls[k*4 + (c - 512)];
        else if (c < 531) { const int q = c - 516; v = Wr[((q/5)*512 + k)*5 + (q%5)]; }
        // fragment-order destination
        const int cb = c >> 7, lc = c & 127;
        const int seg = (cb*16 + (k >> 5))*8 + ((lc >> 5) << 1) + ((lc >> 4) & 1);
        const int di  = (seg*64 + ((k >> 3) & 3)*16 + (lc & 15))*8 + (k & 7);
        wpT[di] = f2bf(v);
    }
    if (tid0 < NCOL2) {
        float v = 0.f; const int c = tid0;
        if (c < 512)      v = (c & 1) ? bb[c >> 1] : ba[c >> 1];
        else if (c < 516) v = bcls[c - 512];
        else if (c < 531) v = br[c - 516];
        ws[OFF_BPACK + c] = v;
    }
    if (tid0 < 128) {
        unsigned* su = (unsigned*)(ws + OFF_SCAL);
        unsigned v = 0u;
        if (tid0 >= SC_FSMIN && tid0 < SC_FSMIN + 4)   v = 0xFFFFFFFFu;
        su[tid0] = v;   // zeroes SC_SUMEXP/YPROB/NUM/CNT/TICKET too
    }
}

// ================= kernel 2: bf16 MFMA GEMM, coalesced fragment-ordered B stream =================
// grid 1563 x 512 thr (8 waves). A fp32->bf16 (NONTEMPORAL h loads) into XOR-swizzled LDS once.
// B: per (wave,nt,step) ONE coalesced 1KB segment load (base+lane*16), depth-2 named-register
// pipeline. Zero barriers in the k-loop. Waves: wm=(w>>2)*32, wn=(w&3)*32, acc 2x2 frags.
__global__ __launch_bounds__(512, 4) void gemm_mfma(
    const float* __restrict__ h, const unsigned short* __restrict__ wpT,
    const float* __restrict__ bpack, const float* __restrict__ Wc,
    const float* __restrict__ bc,
    float* __restrict__ det_logit, float* __restrict__ det_sumexp,
    float* __restrict__ cls_score, float* __restrict__ ref0,
    float* __restrict__ ref1, float* __restrict__ out_ref2)
{
    // smem map (bytes):
    //   [0      .. 65536)  Als [64][512] bf16, XOR-swizzled:
    //                      byte(row,k) = row*1024 + (((k>>3) ^ (row&7))<<4) + (k&7)*2
    //                      slog [64][20] f32 ALIASES Als (cb==4, after barrier)
    //   [65536  .. 68096)  sbias[640]
    //   [68096  .. 72192)  sWc  [1024] (full Wc 256x4)
    //   [72192  .. 73216)  sdet [64][4]
    __shared__ alignas(16) unsigned char smem[73216];
    float* slog  = (float*)smem;
    float* sbias = (float*)(smem + 65536);
    float* sWc   = (float*)(smem + 68096);
    float* sdet  = (float*)(smem + 72192);

    const int tid  = threadIdx.x;       // 0..511
    const int lane = tid & 63;
    const int w    = tid >> 6;          // 0..7
    const int wm   = (w >> 2) * 32;     // {0,32}
    const int wn   = (w & 3) * 32;      // {0,32,64,96}
    const int lrow = lane & 15, lq = lane >> 4;
    const int row_base = blockIdx.x * 64;

    for (int t = tid; t < 640;  t += 512) sbias[t] = bpack[t];
    for (int t = tid; t < 1024; t += 512) sWc[t]   = Wc[t];
    if (tid < 64) { sdet[tid*4+0] = 0.f; sdet[tid*4+1] = 0.f; sdet[tid*4+2] = 0.f; sdet[tid*4+3] = 0.f; }

    // ---- A tile: 64 rows x 512 k, fp32 (nontemporal) -> bf16 into swizzled LDS, once ----
    #pragma unroll
    for (int pass = 0; pass < 2; ++pass) {
        f32x4 tmp[8];
        #pragma unroll
        for (int it = 0; it < 8; ++it) {
            const int q = (pass*8 + it)*512 + tid;       // q in [0, 8192): 64 rows * 128 float4
            const int r = q >> 7, c4 = q & 127;
            const int grow = row_base + r;
            tmp[it] = (grow < NI)
                ? __builtin_nontemporal_load((const f32x4*)&h[(size_t)grow * 512 + c4*4])
                : (f32x4)0.f;
        }
        #pragma unroll
        for (int it = 0; it < 8; ++it) {
            const int q = (pass*8 + it)*512 + tid;
            const int r = q >> 7, c4 = q & 127;
            const int s = (c4 >> 1) ^ (r & 7);           // 16B slot swizzle
            ushort4 pk;
            pk.x = f2bf(tmp[it][0]); pk.y = f2bf(tmp[it][1]);
            pk.z = f2bf(tmp[it][2]); pk.w = f2bf(tmp[it][3]);
            *(ushort4*)(smem + r*1024 + (s<<4) + ((c4&1)<<3)) = pk;
        }
    }
    __syncthreads();

    // A-fragment addressing (per-lane invariant parts)
    const int row0 = wm + lrow;                 // mt=0 row; mt=1 adds 16 rows -> +16384 bytes
    const int r7   = row0 & 7;
    const unsigned abase = (unsigned)(row0*1024 + ((lq ^ (r7 & 3)) << 4));
    const unsigned x64   = (unsigned)((r7 & 4) << 4);    // 0 or 64

    // B segment base for this wave/lane (seg stride 512 elems = 1KB)
    const unsigned short* bbase = wpT + ((w & 3) << 1) * 512 + lane * 8;
    #define BLOAD(cb_, s_, nt_) (*(const uint32x4*)(bbase + (size_t)(((cb_)*16 + (s_))*8 + (nt_)) * 512))

    for (int cb = 0; cb < 5; ++cb) {
        const int n0 = cb * 128;

        f32x4 acc[2][2];
        #pragma unroll
        for (int mt = 0; mt < 2; ++mt)
            #pragma unroll
            for (int nt = 0; nt < 2; ++nt) acc[mt][nt] = (f32x4)0.f;

        uint32x4 b0c = BLOAD(cb, 0, 0), b1c = BLOAD(cb, 0, 1);
        short8 afn0 = *(const short8*)(smem + (abase ^ x64));            // step 0 A frags
        short8 afn1 = *(const short8*)(smem + (abase ^ x64) + 16384);

        #pragma unroll
        for (int s = 0; s < 16; ++s) {
            uint32x4 b0n, b1n;
            if (s + 1 < 16) { b0n = BLOAD(cb, s + 1, 0); b1n = BLOAD(cb, s + 1, 1); }
            const short8 a0 = afn0, a1 = afn1;
            if (s + 1 < 16) {                            // A ds_read one step ahead
                const unsigned aoff = abase + (((unsigned)((s + 1)*64)) ^ x64);
                afn0 = *(const short8*)(smem + aoff);
                afn1 = *(const short8*)(smem + aoff + 16384);
            }
            acc[0][0] = __builtin_amdgcn_mfma_f32_16x16x32_bf16(a0, *(const short8*)&b0c, acc[0][0], 0, 0, 0);
            acc[0][1] = __builtin_amdgcn_mfma_f32_16x16x32_bf16(a0, *(const short8*)&b1c, acc[0][1], 0, 0, 0);
            acc[1][0] = __builtin_amdgcn_mfma_f32_16x16x32_bf16(a1, *(const short8*)&b0c, acc[1][0], 0, 0, 0);
            acc[1][1] = __builtin_amdgcn_mfma_f32_16x16x32_bf16(a1, *(const short8*)&b1c, acc[1][1], 0, 0, 0);
            if (s + 1 < 16) { b0c = b0n; b1c = b1n; }
        }

        if (cb < 4) {
            // gated attention -> det partial; C/D layout col=lane&15, row=lq*4+reg
            #pragma unroll
            for (int mt = 0; mt < 2; ++mt) {
                #pragma unroll
                for (int reg = 0; reg < 4; ++reg) {
                    float c0 = 0.f, c1 = 0.f, c2 = 0.f, c3 = 0.f;
                    #pragma unroll
                    for (int nt = 0; nt < 2; ++nt) {
                        const int cl = wn + nt*16 + lrow;       // local col; parity == lane parity
                        const float v = acc[mt][nt][reg] + sbias[n0 + cl];
                        const float p = __shfl_xor(v, 1);
                        const float ve = (lane & 1) ? p : v;    // Wa logit
                        const float vo = (lane & 1) ? v : p;    // Wb logit
                        const float e2 = __expf(2.f * ve);
                        const float gate = (1.f - 2.f / (e2 + 1.f)) * (1.f / (1.f + __expf(-vo)));
                        if (!(lane & 1)) {                      // even lane owns the pair
                            const int j = (n0 + cl) >> 1;
                            c0 += gate * sWc[j*4+0]; c1 += gate * sWc[j*4+1];
                            c2 += gate * sWc[j*4+2]; c3 += gate * sWc[j*4+3];
                        }
                    }
                    #pragma unroll
                    for (int m = 1; m <= 8; m <<= 1) {
                        c0 += __shfl_xor(c0, m); c1 += __shfl_xor(c1, m);
                        c2 += __shfl_xor(c2, m); c3 += __shfl_xor(c3, m);
                    }
                    if ((lane & 15) == 0) {
                        const int rl = wm + mt*16 + lq*4 + reg;
                        atomicAdd(&sdet[rl*4+0], c0); atomicAdd(&sdet[rl*4+1], c1);
                        atomicAdd(&sdet[rl*4+2], c2); atomicAdd(&sdet[rl*4+3], c3);
                    }
                }
            }
        } else {
            __syncthreads();   // all waves done reading Als -> safe to write aliased slog
            if ((w & 3) == 0) {   // wn==0 waves (w=0,4) hold the 19 real columns
                #pragma unroll
                for (int mt = 0; mt < 2; ++mt)
                    #pragma unroll
                    for (int reg = 0; reg < 4; ++reg)
                        #pragma unroll
                        for (int nt = 0; nt < 2; ++nt) {
                            const int cl = nt*16 + lrow;
                            if (cl < 19) {
                                const int row = wm + mt*16 + lq*4 + reg;
                                slog[row * 20 + cl] = acc[mt][nt][reg] + sbias[512 + cl];
                            }
                        }
            }
            __syncthreads();
            if (tid < 64) {
                const int grow = row_base + tid;
                if (grow < NI) {
                    float L[19];
                    #pragma unroll
                    for (int q = 0; q < 19; ++q) L[q] = slog[tid * 20 + q];
                    {   // cls softmax (cols 0..3)
                        float m = fmaxf(fmaxf(L[0], L[1]), fmaxf(L[2], L[3]));
                        float e0 = __expf(L[0]-m), e1 = __expf(L[1]-m), e2 = __expf(L[2]-m), e3 = __expf(L[3]-m);
                        const float inv = 1.f / (e0 + e1 + e2 + e3);
                        cls_score[(size_t)grow*4+0] = e0*inv; cls_score[(size_t)grow*4+1] = e1*inv;
                        cls_score[(size_t)grow*4+2] = e2*inv; cls_score[(size_t)grow*4+3] = e3*inv;
                    }
                    #pragma unroll
                    for (int r = 0; r < 3; ++r) {
                        float m = L[4+5*r];
                        #pragma unroll
                        for (int e = 1; e < 5; ++e) m = fmaxf(m, L[4+5*r+e]);
                        float ev[5]; float s = 0.f;
                        #pragma unroll
                        for (int e = 0; e < 5; ++e) { ev[e] = __expf(L[4+5*r+e] - m); s += ev[e]; }
                        const float inv = 1.f / s;
                        float* dst = (r == 0) ? ref0 : ((r == 1) ? ref1 : out_ref2);
                        #pragma unroll
                        for (int e = 0; e < 5; ++e) dst[(size_t)grow*5+e] = ev[e] * inv;
                    }
                }
            }
        }
    }
    __syncthreads();

    // det_logit write + per-class exp-sum partial (wave 0 owns all 64 rows)
    if (w == 0) {
        const int grow = row_base + tid;
        float e0 = 0.f, e1 = 0.f, e2 = 0.f, e3 = 0.f;
        const float d0 = sdet[tid*4+0] + bc[0];
        const float d1 = sdet[tid*4+1] + bc[1];
        const float d2 = sdet[tid*4+2] + bc[2];
        const float d3 = sdet[tid*4+3] + bc[3];
        if (grow < NI) {
            float4 dv = make_float4(d0, d1, d2, d3);
            *(float4*)&det_logit[(size_t)grow * 4] = dv;
            e0 = __expf(d0); e1 = __expf(d1); e2 = __expf(d2); e3 = __expf(d3);
        }
        #pragma unroll
        for (int m = 1; m < 64; m <<= 1) {
            e0 += __shfl_xor(e0, m); e1 += __shfl_xor(e1, m);
            e2 += __shfl_xor(e2, m); e3 += __shfl_xor(e3, m);
        }
        if (lane == 0) {
            atomicAdd(&det_sumexp[0], e0); atomicAdd(&det_sumexp[1], e1);
            atomicAdd(&det_sumexp[2], e2); atomicAdd(&det_sumexp[3], e3);
        }
    }
    #undef BLOAD
}

// ================= kernel 3: final_score, mean, Y_prob partials, per-class min/max =================
__global__ __launch_bounds__(256) void final_kernel(const float* __restrict__ det_logit,
        const float* __restrict__ cls_score, const float* __restrict__ det_sumexp,
        float* __restrict__ out_fs, float* __restrict__ mean_sc, float* __restrict__ yprob_sum,
        unsigned* __restrict__ fs_min_enc, unsigned* __restrict__ fs_max_enc)
{
    __shared__ float ssum[4][4], smin[4][4], smax[4][4];
    const int i = blockIdx.x * 256 + threadIdx.x;
    const bool valid = i < NI;
    float f[4]; float tot = 0.f;
    #pragma unroll
    for (int c = 0; c < 4; ++c) {
        float v = 0.f;
        if (valid) {
            const float ds = __expf(det_logit[(size_t)i*4+c]) / det_sumexp[c];
            v = cls_score[(size_t)i*4+c] * ds;
            out_fs[(size_t)i*4+c] = v;
        }
        f[c] = v; tot += v;
    }
    if (valid) mean_sc[i] = 0.25f * tot;
    float sm[4], mn[4], mx[4];
    #pragma unroll
    for (int c = 0; c < 4; ++c) {
        sm[c] = f[c];
        mn[c] = valid ? f[c] : 3.4e38f;
        mx[c] = valid ? f[c] : -3.4e38f;
    }
    #pragma unroll
    for (int c = 0; c < 4; ++c)
        #pragma unroll
        for (int m = 1; m < 64; m <<= 1) {
            sm[c] += __shfl_xor(sm[c], m, 64);
            mn[c] = fminf(mn[c], __shfl_xor(mn[c], m, 64));
            mx[c] = fmaxf(mx[c], __shfl_xor(mx[c], m, 64));
        }
    const int w = threadIdx.x >> 6;
    if ((threadIdx.x & 63) == 0) {
        #pragma unroll
        for (int c = 0; c < 4; ++c) { ssum[w][c] = sm[c]; smin[w][c] = mn[c]; smax[w][c] = mx[c]; }
    }
    __syncthreads();
    if (threadIdx.x < 4) {
        const int c = threadIdx.x;
        float S = 0.f, MN = 3.4e38f, MX = -3.4e38f;
        #pragma unroll
        for (int w2 = 0; w2 < 4; ++w2) {
            S += ssum[w2][c]; MN = fminf(MN, smin[w2][c]); MX = fmaxf(MX, smax[w2][c]);
        }
        atomicAdd(&yprob_sum[c], S);
        atomicMin(&fs_min_enc[c], fenc(MN));
        atomicMax(&fs_max_enc[c], fenc(MX));
    }
}

// ---- selection column accessor: b 0..3 fs, 4 mean(bottom), 5..9 ref0, 10..14 ref1
__device__ __forceinline__ float sel_value(int b, int i, const float* fs, const float* mean,
                                           const float* r0, const float* r1) {
    if (b < 4)  return fs[(size_t)i*4 + b];
    if (b == 4) return mean[i];
    if (b < 10) return r0[(size_t)i*5 + (b-5)];
    return r1[(size_t)i*5 + (b-10)];
}

// ================= kernel 4: FUSED selection: Y_prob/Y_hat + 3 radix passes + collect, per column =================
// 15 independent blocks (one per column); all radix state block-local in LDS. Replaces
// scalars + 3x(hist+scan) + collect = 8 dispatches with 1.
__global__ __launch_bounds__(256) void select_kernel(
        const float* __restrict__ fs, const float* __restrict__ mean,
        const float* __restrict__ r0, const float* __restrict__ r1,
        const int* __restrict__ label, float* __restrict__ out,
        float* __restrict__ ws_scal, int* __restrict__ sel_idx)
{
    float* sf = ws_scal; unsigned* su = (unsigned*)ws_scal; int* si = (int*)ws_scal;
    const int b = blockIdx.x;
    const int tid = threadIdx.x;

    if (b == 0 && tid == 0) {   // absorb scalars_kernel outputs
        float best = -1.f; int arg = 0;
        for (int c2 = 0; c2 < 4; ++c2) {
            float v = sf[SC_YPROB + c2];
            v = fminf(fmaxf(v, 1e-10f), 1.f - 1e-10f);
            out[OUT_YP + c2] = v;
            if (v > best) { best = v; arg = c2; }
        }
        out[OUT_YH] = (float)arg;
    }

    const int c = (b < 4) ? b : ((b == 4) ? -1 : ((b < 10) ? b - 5 : b - 10));
    const int l0 = label[0], l1 = label[1];
    if (c >= 0 && c != 4 && c != l0 && c != l1) return;   // excluded class column

    float thr;
    if (b < 4) {
        const unsigned ue = su[SC_FSMIN + b], ux = su[SC_FSMAX + b];
        const float mn = (ue & 0x80000000u) ? __uint_as_float(ue & 0x7FFFFFFFu) : __uint_as_float(~ue);
        const float mx = (ux & 0x80000000u) ? __uint_as_float(ux & 0x7FFFFFFFu) : __uint_as_float(~ux);
        thr = mn + 0.5f * (mx - mn);
    } else thr = 0.5f;

    __shared__ unsigned lh[HBINS];
    __shared__ unsigned csum[256];
    __shared__ unsigned sbc[2];
    unsigned prefix = 0, K = KSEL;
    const int shifts[3] = {21, 10, 0};
    const int widths[3] = {11, 11, 10};
    for (int p = 0; p < 3; ++p) {
        const int shift = shifts[p], width = widths[p];
        const int nbins = 1 << width;
        const unsigned mask = (unsigned)(nbins - 1);
        const int pb = shift + width;
        for (int t = tid; t < nbins; t += 256) lh[t] = 0u;
        __syncthreads();
        for (int i = tid; i < NI; i += 256) {
            const float v = sel_value(b, i, fs, mean, r0, r1);
            const unsigned u = fenc(b == 4 ? -v : v);
            if (pb >= 32 || (u >> pb) == prefix)
                atomicAdd(&lh[(u >> shift) & mask], 1u);
        }
        __syncthreads();
        const int chunk = (nbins + 255) >> 8;
        unsigned s = 0;
        for (int j = 0; j < chunk; ++j) {
            const int idx = tid * chunk + j;
            if (idx < nbins) s += lh[idx];
        }
        csum[tid] = s;
        __syncthreads();
        if (tid == 0) {
            unsigned running = 0, found = 0, rem = K;
            int t;
            for (t = 255; t >= 0; --t) {
                if (running + csum[t] >= K) break;
                running += csum[t];
            }
            if (t < 0) t = 0;
            for (int j = chunk - 1; j >= 0; --j) {
                const int idx = t * chunk + j;
                if (idx >= nbins) continue;
                const unsigned cc2 = lh[idx];
                if (running + cc2 >= K) { found = (unsigned)idx; rem = K - running; break; }
                running += cc2;
            }
            sbc[0] = (prefix << width) | found;
            sbc[1] = rem;
        }
        __syncthreads();
        prefix = sbc[0]; K = sbc[1];
    }
    const unsigned kth = prefix;   // exact k-th encoded key (32 bits = 11+11+10)
    for (int i = tid; i < NI; i += 256) {
        const float v = sel_value(b, i, fs, mean, r0, r1);
        const unsigned u = fenc(b == 4 ? -v : v);
        const bool cond = (b == 4) ? (v < 0.5f) : (v > thr);
        if (u >= kth && cond) {
            const int pos = atomicAdd(&si[SC_CNT + b], 1);
            if (pos < KSEL) sel_idx[b * KSEL + pos] = i;
        }
    }
}

// ================= kernel 5: CE over selected candidates + fused loss finalize =================
__global__ __launch_bounds__(256) void ce_kernel(const float* __restrict__ h,
        const float* __restrict__ Wr, const float* __restrict__ br,
        const int* __restrict__ sel_idx, float* __restrict__ ws_scal,
        float* __restrict__ out)
{
    int* si = (int*)ws_scal;
    float* sf = ws_scal;
    const int lane = threadIdx.x & 63;
    const int wid = (blockIdx.x * blockDim.x + threadIdx.x) >> 6;
    const int nw = (gridDim.x * blockDim.x) >> 6;
    float l0a = 0.f, l1a = 0.f, l2a = 0.f;
    for (int slot = wid; slot < 15 * KSEL; slot += nw) {
        const int b = slot / KSEL;
        const int j = slot - b * KSEL;
        const int cnt = min(si[SC_CNT + b], KSEL);
        if (j >= cnt) continue;
        const int i = sel_idx[b * KSEL + j];
        const int g = (b < 5) ? 0 : ((b < 10) ? 1 : 2);
        const int tgt = (b < 4) ? b : ((b == 4) ? 4 : ((b < 10) ? (b - 5) : (b - 10)));
        const float* hr = h + (size_t)i * 512;
        const float* wr = Wr + (size_t)g * 512 * 5;
        const int d0 = lane * 8;
        const float4 va = *(const float4*)&hr[d0];
        const float4 vb = *(const float4*)&hr[d0 + 4];
        const float hv[8] = {va.x, va.y, va.z, va.w, vb.x, vb.y, vb.z, vb.w};
        float acc[5] = {0.f, 0.f, 0.f, 0.f, 0.f};
        #pragma unroll
        for (int t = 0; t < 8; ++t) {
            const float* row = wr + (size_t)(d0 + t) * 5;
            #pragma unroll
            for (int e = 0; e < 5; ++e) acc[e] += hv[t] * row[e];
        }
        #pragma unroll
        for (int e = 0; e < 5; ++e)
            #pragma unroll
            for (int m = 1; m < 64; m <<= 1) acc[e] += __shfl_xor(acc[e], m, 64);
        if (lane == 0) {
            float l[5];
            #pragma unroll
            for (int e = 0; e < 5; ++e) l[e] = acc[e] + br[g * 5 + e];
            float mx = l[0];
            #pragma unroll
            for (int e = 1; e < 5; ++e) mx = fmaxf(mx, l[e]);
            float s = 0.f;
            #pragma unroll
            for (int e = 0; e < 5; ++e) s += __expf(l[e] - mx);
            const float ce = logf(s) + mx - l[tgt];
            if (g == 0) l0a += ce; else if (g == 1) l1a += ce; else l2a += ce;
        }
    }
    if (lane == 0) {
        if (l0a != 0.f) atomicAdd(&sf[SC_NUM + 0], l0a);
        if (l1a != 0.f) atomicAdd(&sf[SC_NUM + 1], l1a);
        if (l2a != 0.f) atomicAdd(&sf[SC_NUM + 2], l2a);
    }
    __syncthreads();
    if (threadIdx.x == 0) {   // last block finalizes the loss (device-scope atomic reads)
        __threadfence();
        const unsigned t = atomicAdd(&((unsigned*)ws_scal)[SC_TICKET], 1u);
        if (t == gridDim.x - 1) {
            __threadfence();
            float loss = 0.f;
            for (int g = 0; g < 3; ++g) {
                int den = 0;
                for (int b2 = g * 5; b2 < g * 5 + 5; ++b2)
                    den += min(atomicAdd(&si[SC_CNT + b2], 0), KSEL);
                const float num = atomicAdd(&sf[SC_NUM + g], 0.f);
                loss += num / (float)(den > 1 ? den : 1);
            }
            out[OUT_LOSS] = loss;
        }
    }
}

// ================= launch =================
extern "C" void kernel_launch(void* const* d_in, const int* in_sizes, int n_in,
                              void* d_out, int out_size, void* d_ws, size_t ws_size,
                              hipStream_t stream)
{
    const float* h    = (const float*)d_in[0];
    const int*   lab  = (const int*)d_in[1];
    const float* Wa   = (const float*)d_in[2];
    const float* ba   = (const float*)d_in[3];
    const float* Wb   = (const float*)d_in[4];
    const float* bb   = (const float*)d_in[5];
    const float* Wc   = (const float*)d_in[6];
    const float* bc   = (const float*)d_in[7];
    const float* Wcls = (const float*)d_in[8];
    const float* bcls = (const float*)d_in[9];
    const float* Wr   = (const float*)d_in[10];
    const float* br   = (const float*)d_in[11];
    float* out = (float*)d_out;
    float* ws  = (float*)d_ws;

    float* det_logit = ws + OFF_DET;
    float* cls_score = ws + OFF_CLS;
    float* ref0      = ws + OFF_REF0;
    float* ref1      = ws + OFF_REF1;
    float* mean_sc   = ws + OFF_MEAN;
    unsigned short* wpT = (unsigned short*)(ws + OFF_WPT);
    float* scal = ws + OFF_SCAL;
    int*   sel_idx = (int*)(ws + OFF_SELIDX);

    hipLaunchKernelGGL(prep_kernel, dim3(1280), dim3(256), 0, stream,
                       Wa, Wb, Wcls, Wr, ba, bb, bcls, br, ws);
    hipLaunchKernelGGL(gemm_mfma, dim3(1563), dim3(512), 0, stream,
                       h, wpT, ws + OFF_BPACK, Wc, bc,
                       det_logit, scal + SC_SUMEXP, cls_score, ref0, ref1, out + OUT_REF);
    hipLaunchKernelGGL(final_kernel, dim3(391), dim3(256), 0, stream,
                       det_logit, cls_score, scal + SC_SUMEXP,
                       out + OUT_FS, mean_sc, scal + SC_YPROB,
                       (unsigned*)(scal) + SC_FSMIN, (unsigned*)(scal) + SC_FSMAX);
    hipLaunchKernelGGL(select_kernel, dim3(15), dim3(256), 0, stream,
                       out + OUT_FS, mean_sc, ref0, ref1, lab, out, scal, sel_idx);
    hipLaunchKernelGGL(ce_kernel, dim3(240), dim3(256), 0, stream,
                       h, Wr, br, sel_idx, scal, out);
}

// Round 6
// 616.699 us; speedup vs baseline: 1.6789x; 1.6789x over previous
//
#include <hip/hip_runtime.h>
#include <math.h>

// ---------------- problem constants ----------------
#define NI    100000
#define KSEL  1000
#define NCOL2 640          // packed cols: 512 interleaved Wa/Wb pairs | 4 Wcls | 15 Wr | 109 pad
#define SELY  24           // y-blocks per selection column

// ---------------- d_out layout (floats) ----------------
#define OUT_FS   0
#define OUT_YP   400000
#define OUT_YH   400004
#define OUT_REF  400005
#define OUT_LOSS 900005

// ---------------- workspace layout (float offsets) ----------------
#define OFF_DET    0                 // det_logit N*4
#define OFF_CLS    400000            // cls_score N*4
#define OFF_REF0   800000            // softmax(h@Wr0+br0) N*5
#define OFF_REF1   1300000           // softmax(h@Wr1+br1) N*5
#define OFF_MEAN   1800000           // mean_score N
#define OFF_WPT    1900000           // bf16 packed W^T, FRAGMENT-ORDERED = 640KB; radix hists
                                     // ALIAS this region after gemm (zeroed by final_kernel)
#define OFF_BPACK  2063840           // packed bias [640]
#define OFF_SCAL   2064480           // 128 scalar slots
#define OFF_SELIDX 2064608           // 15*1000 ints

// hist aliasing inside OFF_WPT region (u32 offsets from OFF_WPT):
//   hist0: [15][2048] @ 0     hist1: [15][2048] @ 30720     hist2: [15][1024] @ 61440
#define HTOT 76800                   // total u32 = 307KB <= 640KB region

// scalar slots (index into u32/f32/i32 view of ws+OFF_SCAL)
#define SC_SUMEXP 0     // f[4] det softmax denominator
#define SC_YPROB  4     // f[4]
#define SC_FSMIN  8     // u[4] encoded min of final_score per class
#define SC_FSMAX  12    // u[4]
#define SC_NUM    25    // f[3] CE numerators
#define SC_CNT    28    // i[15] selected counts
#define SC_TICKET 73    // u[1] ce last-block ticket

typedef short short8 __attribute__((ext_vector_type(8)));
typedef float f32x4 __attribute__((ext_vector_type(4)));
typedef unsigned int uint32x4 __attribute__((ext_vector_type(4)));

__device__ __forceinline__ unsigned fenc(float x) {
    unsigned u = __float_as_uint(x);
    return (u & 0x80000000u) ? ~u : (u | 0x80000000u);
}
__device__ __forceinline__ unsigned short f2bf(float f) {
    unsigned u = __float_as_uint(f);
    return (unsigned short)((u + 0x7FFFu + ((u >> 16) & 1u)) >> 16);
}

// ================= kernel 1: pack weights bf16 in FRAGMENT ORDER, biases, init scalars =================
// B layout: seg(cb,s,colblk,nt) = (cb*16+s)*8 + colblk*2 + nt, 640 segs x 1KB.
// Within a seg: lane (lq*16+lrow) holds 8 elems = col(colblk*32+nt*16+lrow), k(s*32+lq*8 ..+8).
// -> each k-loop B load is base + lane*16: ONE coalesced 1KB segment.
__global__ __launch_bounds__(256) void prep_kernel(
    const float* __restrict__ Wa, const float* __restrict__ Wb,
    const float* __restrict__ Wcls, const float* __restrict__ Wr,
    const float* __restrict__ ba, const float* __restrict__ bb,
    const float* __restrict__ bcls, const float* __restrict__ br,
    float* __restrict__ ws)
{
    const int tid0 = blockIdx.x * 256 + threadIdx.x;   // grid 1280*256 = 327680 threads
    unsigned short* wpT = (unsigned short*)(ws + OFF_WPT);
    if (tid0 < NCOL2 * 512) {
        const int c = tid0 >> 9, k = tid0 & 511;
        float v = 0.f;
        if (c < 512)      { const int j = c >> 1; v = (c & 1) ? Wb[k*256 + j] : Wa[k*256 + j]; }
        else if (c < 516)   v = Wcls[k*4 + (c - 512)];
        else if (c < 531) { const int q = c - 516; v = Wr[((q/5)*512 + k)*5 + (q%5)]; }
        // fragment-order destination
        const int cb = c >> 7, lc = c & 127;
        const int seg = (cb*16 + (k >> 5))*8 + ((lc >> 5) << 1) + ((lc >> 4) & 1);
        const int di  = (seg*64 + ((k >> 3) & 3)*16 + (lc & 15))*8 + (k & 7);
        wpT[di] = f2bf(v);
    }
    if (tid0 < NCOL2) {
        float v = 0.f; const int c = tid0;
        if (c < 512)      v = (c & 1) ? bb[c >> 1] : ba[c >> 1];
        else if (c < 516) v = bcls[c - 512];
        else if (c < 531) v = br[c - 516];
        ws[OFF_BPACK + c] = v;
    }
    if (tid0 < 128) {
        unsigned* su = (unsigned*)(ws + OFF_SCAL);
        unsigned v = 0u;
        if (tid0 >= SC_FSMIN && tid0 < SC_FSMIN + 4)   v = 0xFFFFFFFFu;
        su[tid0] = v;   // zeroes SC_SUMEXP/YPROB/NUM/CNT/TICKET too
    }
}

// ================= kernel 2: bf16 MFMA GEMM, coalesced fragment-ordered B stream =================
// grid 1563 x 512 thr (8 waves). A fp32->bf16 (nontemporal) into XOR-swizzled LDS once.
// B: per (wave,nt,step) ONE coalesced 1KB segment load (base+lane*16), depth-2 named-register
// pipeline. Zero barriers in the k-loop. Waves: wm=(w>>2)*32, wn=(w&3)*32, acc 2x2 frags.
__global__ __launch_bounds__(512, 4) void gemm_mfma(
    const float* __restrict__ h, const unsigned short* __restrict__ wpT,
    const float* __restrict__ bpack, const float* __restrict__ Wc,
    const float* __restrict__ bc,
    float* __restrict__ det_logit, float* __restrict__ det_sumexp,
    float* __restrict__ cls_score, float* __restrict__ ref0,
    float* __restrict__ ref1, float* __restrict__ out_ref2)
{
    __shared__ alignas(16) unsigned char smem[73216];
    float* slog  = (float*)smem;
    float* sbias = (float*)(smem + 65536);
    float* sWc   = (float*)(smem + 68096);
    float* sdet  = (float*)(smem + 72192);

    const int tid  = threadIdx.x;       // 0..511
    const int lane = tid & 63;
    const int w    = tid >> 6;          // 0..7
    const int wm   = (w >> 2) * 32;     // {0,32}
    const int wn   = (w & 3) * 32;      // {0,32,64,96}
    const int lrow = lane & 15, lq = lane >> 4;
    const int row_base = blockIdx.x * 64;

    for (int t = tid; t < 640;  t += 512) sbias[t] = bpack[t];
    for (int t = tid; t < 1024; t += 512) sWc[t]   = Wc[t];
    if (tid < 64) { sdet[tid*4+0] = 0.f; sdet[tid*4+1] = 0.f; sdet[tid*4+2] = 0.f; sdet[tid*4+3] = 0.f; }

    // ---- A tile: 64 rows x 512 k, fp32 (nontemporal) -> bf16 into swizzled LDS, once ----
    #pragma unroll
    for (int pass = 0; pass < 2; ++pass) {
        f32x4 tmp[8];
        #pragma unroll
        for (int it = 0; it < 8; ++it) {
            const int q = (pass*8 + it)*512 + tid;
            const int r = q >> 7, c4 = q & 127;
            const int grow = row_base + r;
            tmp[it] = (grow < NI)
                ? __builtin_nontemporal_load((const f32x4*)&h[(size_t)grow * 512 + c4*4])
                : (f32x4)0.f;
        }
        #pragma unroll
        for (int it = 0; it < 8; ++it) {
            const int q = (pass*8 + it)*512 + tid;
            const int r = q >> 7, c4 = q & 127;
            const int s = (c4 >> 1) ^ (r & 7);
            ushort4 pk;
            pk.x = f2bf(tmp[it][0]); pk.y = f2bf(tmp[it][1]);
            pk.z = f2bf(tmp[it][2]); pk.w = f2bf(tmp[it][3]);
            *(ushort4*)(smem + r*1024 + (s<<4) + ((c4&1)<<3)) = pk;
        }
    }
    __syncthreads();

    const int row0 = wm + lrow;
    const int r7   = row0 & 7;
    const unsigned abase = (unsigned)(row0*1024 + ((lq ^ (r7 & 3)) << 4));
    const unsigned x64   = (unsigned)((r7 & 4) << 4);

    const unsigned short* bbase = wpT + ((w & 3) << 1) * 512 + lane * 8;
    #define BLOAD(cb_, s_, nt_) (*(const uint32x4*)(bbase + (size_t)(((cb_)*16 + (s_))*8 + (nt_)) * 512))

    for (int cb = 0; cb < 5; ++cb) {
        const int n0 = cb * 128;

        f32x4 acc[2][2];
        #pragma unroll
        for (int mt = 0; mt < 2; ++mt)
            #pragma unroll
            for (int nt = 0; nt < 2; ++nt) acc[mt][nt] = (f32x4)0.f;

        uint32x4 b0c = BLOAD(cb, 0, 0), b1c = BLOAD(cb, 0, 1);
        short8 afn0 = *(const short8*)(smem + (abase ^ x64));
        short8 afn1 = *(const short8*)(smem + (abase ^ x64) + 16384);

        #pragma unroll
        for (int s = 0; s < 16; ++s) {
            uint32x4 b0n, b1n;
            if (s + 1 < 16) { b0n = BLOAD(cb, s + 1, 0); b1n = BLOAD(cb, s + 1, 1); }
            const short8 a0 = afn0, a1 = afn1;
            if (s + 1 < 16) {
                const unsigned aoff = abase + (((unsigned)((s + 1)*64)) ^ x64);
                afn0 = *(const short8*)(smem + aoff);
                afn1 = *(const short8*)(smem + aoff + 16384);
            }
            acc[0][0] = __builtin_amdgcn_mfma_f32_16x16x32_bf16(a0, *(const short8*)&b0c, acc[0][0], 0, 0, 0);
            acc[0][1] = __builtin_amdgcn_mfma_f32_16x16x32_bf16(a0, *(const short8*)&b1c, acc[0][1], 0, 0, 0);
            acc[1][0] = __builtin_amdgcn_mfma_f32_16x16x32_bf16(a1, *(const short8*)&b0c, acc[1][0], 0, 0, 0);
            acc[1][1] = __builtin_amdgcn_mfma_f32_16x16x32_bf16(a1, *(const short8*)&b1c, acc[1][1], 0, 0, 0);
            if (s + 1 < 16) { b0c = b0n; b1c = b1n; }
        }

        if (cb < 4) {
            #pragma unroll
            for (int mt = 0; mt < 2; ++mt) {
                #pragma unroll
                for (int reg = 0; reg < 4; ++reg) {
                    float c0 = 0.f, c1 = 0.f, c2 = 0.f, c3 = 0.f;
                    #pragma unroll
                    for (int nt = 0; nt < 2; ++nt) {
                        const int cl = wn + nt*16 + lrow;
                        const float v = acc[mt][nt][reg] + sbias[n0 + cl];
                        const float p = __shfl_xor(v, 1);
                        const float ve = (lane & 1) ? p : v;
                        const float vo = (lane & 1) ? v : p;
                        const float e2 = __expf(2.f * ve);
                        const float gate = (1.f - 2.f / (e2 + 1.f)) * (1.f / (1.f + __expf(-vo)));
                        if (!(lane & 1)) {
                            const int j = (n0 + cl) >> 1;
                            c0 += gate * sWc[j*4+0]; c1 += gate * sWc[j*4+1];
                            c2 += gate * sWc[j*4+2]; c3 += gate * sWc[j*4+3];
                        }
                    }
                    #pragma unroll
                    for (int m = 1; m <= 8; m <<= 1) {
                        c0 += __shfl_xor(c0, m); c1 += __shfl_xor(c1, m);
                        c2 += __shfl_xor(c2, m); c3 += __shfl_xor(c3, m);
                    }
                    if ((lane & 15) == 0) {
                        const int rl = wm + mt*16 + lq*4 + reg;
                        atomicAdd(&sdet[rl*4+0], c0); atomicAdd(&sdet[rl*4+1], c1);
                        atomicAdd(&sdet[rl*4+2], c2); atomicAdd(&sdet[rl*4+3], c3);
                    }
                }
            }
        } else {
            __syncthreads();
            if ((w & 3) == 0) {
                #pragma unroll
                for (int mt = 0; mt < 2; ++mt)
                    #pragma unroll
                    for (int reg = 0; reg < 4; ++reg)
                        #pragma unroll
                        for (int nt = 0; nt < 2; ++nt) {
                            const int cl = nt*16 + lrow;
                            if (cl < 19) {
                                const int row = wm + mt*16 + lq*4 + reg;
                                slog[row * 20 + cl] = acc[mt][nt][reg] + sbias[512 + cl];
                            }
                        }
            }
            __syncthreads();
            if (tid < 64) {
                const int grow = row_base + tid;
                if (grow < NI) {
                    float L[19];
                    #pragma unroll
                    for (int q = 0; q < 19; ++q) L[q] = slog[tid * 20 + q];
                    {
                        float m = fmaxf(fmaxf(L[0], L[1]), fmaxf(L[2], L[3]));
                        float e0 = __expf(L[0]-m), e1 = __expf(L[1]-m), e2 = __expf(L[2]-m), e3 = __expf(L[3]-m);
                        const float inv = 1.f / (e0 + e1 + e2 + e3);
                        cls_score[(size_t)grow*4+0] = e0*inv; cls_score[(size_t)grow*4+1] = e1*inv;
                        cls_score[(size_t)grow*4+2] = e2*inv; cls_score[(size_t)grow*4+3] = e3*inv;
                    }
                    #pragma unroll
                    for (int r = 0; r < 3; ++r) {
                        float m = L[4+5*r];
                        #pragma unroll
                        for (int e = 1; e < 5; ++e) m = fmaxf(m, L[4+5*r+e]);
                        float ev[5]; float s = 0.f;
                        #pragma unroll
                        for (int e = 0; e < 5; ++e) { ev[e] = __expf(L[4+5*r+e] - m); s += ev[e]; }
                        const float inv = 1.f / s;
                        float* dst = (r == 0) ? ref0 : ((r == 1) ? ref1 : out_ref2);
                        #pragma unroll
                        for (int e = 0; e < 5; ++e) dst[(size_t)grow*5+e] = ev[e] * inv;
                    }
                }
            }
        }
    }
    __syncthreads();

    if (w == 0) {
        const int grow = row_base + tid;
        float e0 = 0.f, e1 = 0.f, e2 = 0.f, e3 = 0.f;
        const float d0 = sdet[tid*4+0] + bc[0];
        const float d1 = sdet[tid*4+1] + bc[1];
        const float d2 = sdet[tid*4+2] + bc[2];
        const float d3 = sdet[tid*4+3] + bc[3];
        if (grow < NI) {
            float4 dv = make_float4(d0, d1, d2, d3);
            *(float4*)&det_logit[(size_t)grow * 4] = dv;
            e0 = __expf(d0); e1 = __expf(d1); e2 = __expf(d2); e3 = __expf(d3);
        }
        #pragma unroll
        for (int m = 1; m < 64; m <<= 1) {
            e0 += __shfl_xor(e0, m); e1 += __shfl_xor(e1, m);
            e2 += __shfl_xor(e2, m); e3 += __shfl_xor(e3, m);
        }
        if (lane == 0) {
            atomicAdd(&det_sumexp[0], e0); atomicAdd(&det_sumexp[1], e1);
            atomicAdd(&det_sumexp[2], e2); atomicAdd(&det_sumexp[3], e3);
        }
    }
    #undef BLOAD
}

// ================= kernel 3: final_score, mean, Y_prob partials, min/max + hist zero =================
__global__ __launch_bounds__(256) void final_kernel(const float* __restrict__ det_logit,
        const float* __restrict__ cls_score, const float* __restrict__ det_sumexp,
        float* __restrict__ out_fs, float* __restrict__ mean_sc, float* __restrict__ yprob_sum,
        unsigned* __restrict__ fs_min_enc, unsigned* __restrict__ fs_max_enc,
        unsigned* __restrict__ histz)
{
    __shared__ float ssum[4][4], smin[4][4], smax[4][4];
    const int i = blockIdx.x * 256 + threadIdx.x;
    if (i < HTOT) histz[i] = 0u;        // zero radix hists (aliases dead wpT region)
    const bool valid = i < NI;
    float f[4]; float tot = 0.f;
    #pragma unroll
    for (int c = 0; c < 4; ++c) {
        float v = 0.f;
        if (valid) {
            const float ds = __expf(det_logit[(size_t)i*4+c]) / det_sumexp[c];
            v = cls_score[(size_t)i*4+c] * ds;
            out_fs[(size_t)i*4+c] = v;
        }
        f[c] = v; tot += v;
    }
    if (valid) mean_sc[i] = 0.25f * tot;
    float sm[4], mn[4], mx[4];
    #pragma unroll
    for (int c = 0; c < 4; ++c) {
        sm[c] = f[c];
        mn[c] = valid ? f[c] : 3.4e38f;
        mx[c] = valid ? f[c] : -3.4e38f;
    }
    #pragma unroll
    for (int c = 0; c < 4; ++c)
        #pragma unroll
        for (int m = 1; m < 64; m <<= 1) {
            sm[c] += __shfl_xor(sm[c], m, 64);
            mn[c] = fminf(mn[c], __shfl_xor(mn[c], m, 64));
            mx[c] = fmaxf(mx[c], __shfl_xor(mx[c], m, 64));
        }
    const int w = threadIdx.x >> 6;
    if ((threadIdx.x & 63) == 0) {
        #pragma unroll
        for (int c = 0; c < 4; ++c) { ssum[w][c] = sm[c]; smin[w][c] = mn[c]; smax[w][c] = mx[c]; }
    }
    __syncthreads();
    if (threadIdx.x < 4) {
        const int c = threadIdx.x;
        float S = 0.f, MN = 3.4e38f, MX = -3.4e38f;
        #pragma unroll
        for (int w2 = 0; w2 < 4; ++w2) {
            S += ssum[w2][c]; MN = fminf(MN, smin[w2][c]); MX = fmaxf(MX, smax[w2][c]);
        }
        atomicAdd(&yprob_sum[c], S);
        atomicMin(&fs_min_enc[c], fenc(MN));
        atomicMax(&fs_max_enc[c], fenc(MX));
    }
}

// ---- selection column accessor: b 0..3 fs, 4 mean(bottom), 5..9 ref0, 10..14 ref1
__device__ __forceinline__ float sel_value(int b, int i, const float* fs, const float* mean,
                                           const float* r0, const float* r1) {
    if (b < 4)  return fs[(size_t)i*4 + b];
    if (b == 4) return mean[i];
    if (b < 10) return r0[(size_t)i*5 + (b-5)];
    return r1[(size_t)i*5 + (b-10)];
}

// ---- cooperative in-block suffix-scan of a completed global histogram; broadcasts result.
// Every block recomputes this redundantly (cheap) -> no cross-dispatch scan kernels needed.
__device__ __forceinline__ void scan_hist(const unsigned* __restrict__ hh, int nbins, int width,
                                          unsigned* prefix, unsigned* K,
                                          unsigned* csum, unsigned* sres, int tid)
{
    __syncthreads();                       // csum/sres reuse safety
    const int chunk = nbins >> 8;
    unsigned s = 0;
    for (int j = 0; j < chunk; ++j) s += hh[tid*chunk + j];
    csum[tid] = s;
    __syncthreads();
    if (tid == 0) {
        const unsigned Kv = *K;
        unsigned running = 0, found = 0, rem = Kv;
        int t;
        for (t = 255; t >= 0; --t) {
            if (running + csum[t] >= Kv) break;
            running += csum[t];
        }
        if (t < 0) t = 0;                  // degenerate (empty hist)
        for (int j = chunk - 1; j >= 0; --j) {
            const unsigned cc = hh[t*chunk + j];
            if (running + cc >= Kv) { found = (unsigned)(t*chunk + j); rem = Kv - running; break; }
            running += cc;
        }
        sres[0] = found; sres[1] = rem;
    }
    __syncthreads();
    *prefix = ((*prefix) << width) | sres[0];
    *K = sres[1];
}

// ================= kernel 4: radix histogram pass p (0,1,2), grid (15, SELY) =================
__global__ __launch_bounds__(256) void hist_kernel(
        const float* __restrict__ fs, const float* __restrict__ mean,
        const float* __restrict__ r0, const float* __restrict__ r1,
        const int* __restrict__ label, float* __restrict__ out,
        const float* __restrict__ ws_scal, unsigned* __restrict__ H, int pass)
{
    const int b = blockIdx.x, tid = threadIdx.x;
    if (pass == 0 && b == 0 && blockIdx.y == 0 && tid == 0) {   // absorb scalars_kernel
        const float* sf = ws_scal;
        float best = -1.f; int arg = 0;
        for (int c2 = 0; c2 < 4; ++c2) {
            float v = sf[SC_YPROB + c2];
            v = fminf(fmaxf(v, 1e-10f), 1.f - 1e-10f);
            out[OUT_YP + c2] = v;
            if (v > best) { best = v; arg = c2; }
        }
        out[OUT_YH] = (float)arg;
    }
    const int c = (b < 4) ? b : ((b == 4) ? -1 : ((b < 10) ? b - 5 : b - 10));
    if (c >= 0 && c != 4 && c != label[0] && c != label[1]) return;

    __shared__ unsigned lh[2048];
    __shared__ unsigned csum[256];
    __shared__ unsigned sres[2];
    unsigned prefix = 0, K = KSEL;
    if (pass >= 1) scan_hist(H + b*2048,         2048, 11, &prefix, &K, csum, sres, tid);
    if (pass >= 2) scan_hist(H + 30720 + b*2048, 2048, 11, &prefix, &K, csum, sres, tid);

    const int shift = (pass == 0) ? 21 : ((pass == 1) ? 10 : 0);
    const int width = (pass == 2) ? 10 : 11;
    const int nbins = 1 << width;
    unsigned* dst = (pass == 0) ? H + b*2048
                  : (pass == 1) ? H + 30720 + b*2048
                                : H + 61440 + b*1024;
    for (int t = tid; t < nbins; t += 256) lh[t] = 0u;
    __syncthreads();
    const int pb = shift + width;
    const unsigned mask = (unsigned)(nbins - 1);
    for (int i = blockIdx.y * 256 + tid; i < NI; i += SELY * 256) {
        const float v = sel_value(b, i, fs, mean, r0, r1);
        const unsigned u = fenc(b == 4 ? -v : v);
        if (pb >= 32 || (u >> pb) == prefix)
            atomicAdd(&lh[(u >> shift) & mask], 1u);
    }
    __syncthreads();
    for (int t = tid; t < nbins; t += 256)
        if (lh[t]) atomicAdd(&dst[t], lh[t]);
}

// ================= kernel 5: collect selected indices, grid (15, SELY) =================
__global__ __launch_bounds__(256) void collect_kernel(
        const float* __restrict__ fs, const float* __restrict__ mean,
        const float* __restrict__ r0, const float* __restrict__ r1,
        const int* __restrict__ label, float* __restrict__ ws_scal,
        const unsigned* __restrict__ H, int* __restrict__ sel_idx)
{
    const int b = blockIdx.x, tid = threadIdx.x;
    const int c = (b < 4) ? b : ((b == 4) ? -1 : ((b < 10) ? b - 5 : b - 10));
    if (c >= 0 && c != 4 && c != label[0] && c != label[1]) return;
    unsigned* su = (unsigned*)ws_scal; int* si = (int*)ws_scal;

    __shared__ unsigned csum[256];
    __shared__ unsigned sres[2];
    unsigned prefix = 0, K = KSEL;
    scan_hist(H + b*2048,         2048, 11, &prefix, &K, csum, sres, tid);
    scan_hist(H + 30720 + b*2048, 2048, 11, &prefix, &K, csum, sres, tid);
    scan_hist(H + 61440 + b*1024, 1024, 10, &prefix, &K, csum, sres, tid);
    const unsigned kth = prefix;   // exact k-th encoded key (11+11+10 = 32 bits)

    float thr;
    if (b < 4) {
        const unsigned ue = su[SC_FSMIN + b], ux = su[SC_FSMAX + b];
        const float mn = (ue & 0x80000000u) ? __uint_as_float(ue & 0x7FFFFFFFu) : __uint_as_float(~ue);
        const float mx = (ux & 0x80000000u) ? __uint_as_float(ux & 0x7FFFFFFFu) : __uint_as_float(~ux);
        thr = mn + 0.5f * (mx - mn);
    } else thr = 0.5f;

    for (int i = blockIdx.y * 256 + tid; i < NI; i += SELY * 256) {
        const float v = sel_value(b, i, fs, mean, r0, r1);
        const unsigned u = fenc(b == 4 ? -v : v);
        const bool cond = (b == 4) ? (v < 0.5f) : (v > thr);
        if (u >= kth && cond) {
            const int pos = atomicAdd(&si[SC_CNT + b], 1);
            if (pos < KSEL) sel_idx[b * KSEL + pos] = i;
        }
    }
}

// ================= kernel 6: CE over selected candidates + fused loss finalize =================
__global__ __launch_bounds__(256) void ce_kernel(const float* __restrict__ h,
        const float* __restrict__ Wr, const float* __restrict__ br,
        const int* __restrict__ sel_idx, float* __restrict__ ws_scal,
        float* __restrict__ out)
{
    int* si = (int*)ws_scal;
    float* sf = ws_scal;
    const int lane = threadIdx.x & 63;
    const int wid = (blockIdx.x * blockDim.x + threadIdx.x) >> 6;
    const int nw = (gridDim.x * blockDim.x) >> 6;
    float l0a = 0.f, l1a = 0.f, l2a = 0.f;
    for (int slot = wid; slot < 15 * KSEL; slot += nw) {
        const int b = slot / KSEL;
        const int j = slot - b * KSEL;
        const int cnt = min(si[SC_CNT + b], KSEL);
        if (j >= cnt) continue;
        const int i = sel_idx[b * KSEL + j];
        const int g = (b < 5) ? 0 : ((b < 10) ? 1 : 2);
        const int tgt = (b < 4) ? b : ((b == 4) ? 4 : ((b < 10) ? (b - 5) : (b - 10)));
        const float* hr = h + (size_t)i * 512;
        const float* wr = Wr + (size_t)g * 512 * 5;
        const int d0 = lane * 8;
        const float4 va = *(const float4*)&hr[d0];
        const float4 vb = *(const float4*)&hr[d0 + 4];
        const float hv[8] = {va.x, va.y, va.z, va.w, vb.x, vb.y, vb.z, vb.w};
        float acc[5] = {0.f, 0.f, 0.f, 0.f, 0.f};
        #pragma unroll
        for (int t = 0; t < 8; ++t) {
            const float* row = wr + (size_t)(d0 + t) * 5;
            #pragma unroll
            for (int e = 0; e < 5; ++e) acc[e] += hv[t] * row[e];
        }
        #pragma unroll
        for (int e = 0; e < 5; ++e)
            #pragma unroll
            for (int m = 1; m < 64; m <<= 1) acc[e] += __shfl_xor(acc[e], m, 64);
        if (lane == 0) {
            float l[5];
            #pragma unroll
            for (int e = 0; e < 5; ++e) l[e] = acc[e] + br[g * 5 + e];
            float mx = l[0];
            #pragma unroll
            for (int e = 1; e < 5; ++e) mx = fmaxf(mx, l[e]);
            float s = 0.f;
            #pragma unroll
            for (int e = 0; e < 5; ++e) s += __expf(l[e] - mx);
            const float ce = logf(s) + mx - l[tgt];
            if (g == 0) l0a += ce; else if (g == 1) l1a += ce; else l2a += ce;
        }
    }
    if (lane == 0) {
        if (l0a != 0.f) atomicAdd(&sf[SC_NUM + 0], l0a);
        if (l1a != 0.f) atomicAdd(&sf[SC_NUM + 1], l1a);
        if (l2a != 0.f) atomicAdd(&sf[SC_NUM + 2], l2a);
    }
    __syncthreads();
    if (threadIdx.x == 0) {   // last block finalizes the loss (device-scope atomic reads)
        __threadfence();
        const unsigned t = atomicAdd(&((unsigned*)ws_scal)[SC_TICKET], 1u);
        if (t == gridDim.x - 1) {
            __threadfence();
            float loss = 0.f;
            for (int g = 0; g < 3; ++g) {
                int den = 0;
                for (int b2 = g * 5; b2 < g * 5 + 5; ++b2)
                    den += min(atomicAdd(&si[SC_CNT + b2], 0), KSEL);
                const float num = atomicAdd(&sf[SC_NUM + g], 0.f);
                loss += num / (float)(den > 1 ? den : 1);
            }
            out[OUT_LOSS] = loss;
        }
    }
}

// ================= launch =================
extern "C" void kernel_launch(void* const* d_in, const int* in_sizes, int n_in,
                              void* d_out, int out_size, void* d_ws, size_t ws_size,
                              hipStream_t stream)
{
    const float* h    = (const float*)d_in[0];
    const int*   lab  = (const int*)d_in[1];
    const float* Wa   = (const float*)d_in[2];
    const float* ba   = (const float*)d_in[3];
    const float* Wb   = (const float*)d_in[4];
    const float* bb   = (const float*)d_in[5];
    const float* Wc   = (const float*)d_in[6];
    const float* bc   = (const float*)d_in[7];
    const float* Wcls = (const float*)d_in[8];
    const float* bcls = (const float*)d_in[9];
    const float* Wr   = (const float*)d_in[10];
    const float* br   = (const float*)d_in[11];
    float* out = (float*)d_out;
    float* ws  = (float*)d_ws;

    float* det_logit = ws + OFF_DET;
    float* cls_score = ws + OFF_CLS;
    float* ref0      = ws + OFF_REF0;
    float* ref1      = ws + OFF_REF1;
    float* mean_sc   = ws + OFF_MEAN;
    unsigned short* wpT = (unsigned short*)(ws + OFF_WPT);
    unsigned* H = (unsigned*)(ws + OFF_WPT);   // hists alias wpT after gemm
    float* scal = ws + OFF_SCAL;
    int*   sel_idx = (int*)(ws + OFF_SELIDX);

    hipLaunchKernelGGL(prep_kernel, dim3(1280), dim3(256), 0, stream,
                       Wa, Wb, Wcls, Wr, ba, bb, bcls, br, ws);
    hipLaunchKernelGGL(gemm_mfma, dim3(1563), dim3(512), 0, stream,
                       h, wpT, ws + OFF_BPACK, Wc, bc,
                       det_logit, scal + SC_SUMEXP, cls_score, ref0, ref1, out + OUT_REF);
    hipLaunchKernelGGL(final_kernel, dim3(391), dim3(256), 0, stream,
                       det_logit, cls_score, scal + SC_SUMEXP,
                       out + OUT_FS, mean_sc, scal + SC_YPROB,
                       (unsigned*)(scal) + SC_FSMIN, (unsigned*)(scal) + SC_FSMAX, H);
    hipLaunchKernelGGL(hist_kernel, dim3(15, SELY), dim3(256), 0, stream,
                       out + OUT_FS, mean_sc, ref0, ref1, lab, out, scal, H, 0);
    hipLaunchKernelGGL(hist_kernel, dim3(15, SELY), dim3(256), 0, stream,
                       out + OUT_FS, mean_sc, ref0, ref1, lab, out, scal, H, 1);
    hipLaunchKernelGGL(hist_kernel, dim3(15, SELY), dim3(256), 0, stream,
                       out + OUT_FS, mean_sc, ref0, ref1, lab, out, scal, H, 2);
    hipLaunchKernelGGL(collect_kernel, dim3(15, SELY), dim3(256), 0, stream,
                       out + OUT_FS, mean_sc, ref0, ref1, lab, scal, H, sel_idx);
    hipLaunchKernelGGL(ce_kernel, dim3(240), dim3(256), 0, stream,
                       h, Wr, br, sel_idx, scal, out);
}